// Round 12
// baseline (439.587 us; speedup 1.0000x reference)
//
#include <hip/hip_runtime.h>
#include <hip/hip_cooperative_groups.h>

namespace cg = cooperative_groups;

// Head: single-head causal attention. B=4, T=2048, D=1024, H=64. fp32 in/out.
// R12: R11 fused cooperative kernel with (a) __launch_bounds__(256,2) to cap
// VGPR<=256 so 512 blocks co-reside (R11's silent-failure theory: coop launch
// rejected for too-large grid), and (b) error-checked fallback to the R9
// 4-launch path (known 106us) if the coop launch is refused.
//
// ws layout (bytes):
//   [0,        393216)   wtf   bf16 [12][128][16][8]
//   [393216,  1441792)   qf    bf16 [512][8][16][8]
//   [1441792, 2490368)   kf    bf16 [512][8][16][8]
//   [2490368, 3538944)   vf    bf16 [4][32][4][8][16][8]
//   [3538944, 12451840)  Opart bf16 [4352][16][64]
//   [12451840,12730368)  mpart fp32 [4352][16]
//   [12730368,13008896)  lpart fp32 [4352][16]

typedef __attribute__((ext_vector_type(8))) __bf16 bf16x8;
typedef __attribute__((ext_vector_type(4))) float floatx4;

union BF8 {
    bf16x8 v;
    unsigned short s[8];
    uint4 u;
};
union BF4 {
    unsigned short s[4];
    unsigned long long ull;
};

__device__ inline unsigned short f2bf(float f) {
    unsigned int u = __float_as_uint(f);
    unsigned int r = (u + 0x7fffu + ((u >> 16) & 1u)) >> 16;
    return (unsigned short)r;
}
__device__ inline float bf2f(unsigned short s) {
    unsigned int u = ((unsigned int)s) << 16;
    return __uint_as_float(u);
}

// ========================= shared phase bodies =========================

__device__ __forceinline__ void phase_wtf(int bid, int tid, unsigned short* lt,
                                          const float* Wq, const float* Wk,
                                          const float* Wv, unsigned short* wtf) {
    const int sel = bid >> 4;
    const int kb = bid & 15;
    const float* W = (sel == 0) ? Wq : (sel == 1) ? Wk : Wv;
    const int h = tid & 63;
    const int kr = tid >> 6;
#pragma unroll
    for (int i = 0; i < 16; ++i) {
        const int kkl = kr + i * 4;
        lt[kkl * 72 + h] = f2bf(W[(size_t)(kb * 64 + kkl) * 64 + h]);
    }
    __syncthreads();
#pragma unroll
    for (int s = 0; s < 2; ++s) {
        const int seg = tid + s * 256;
        const int sl16 = seg & 15;
        const int rest = seg >> 4;
        const int ko = rest & 7;
        const int hb = rest >> 3;
        const int hh = hb * 16 + sl16;
        BF8 o;
#pragma unroll
        for (int j = 0; j < 8; ++j) o.s[j] = lt[(ko * 8 + j) * 72 + hh];
        const int nblk = sel * 4 + hb;
        const int koct = kb * 8 + ko;
        *(uint4*)(wtf + ((size_t)nblk * 128 + koct) * 128 + sl16 * 8) = o.u;
    }
}

__device__ __forceinline__ void phase_qkv(int bid, int tid, unsigned short* smem,
                                          const float* x, const unsigned short* wtf,
                                          unsigned short* qf, unsigned short* kf,
                                          unsigned short* vf) {
    unsigned short* lx0 = smem;
    unsigned short* lx1 = smem + 16 * 136;
    unsigned short* lt = smem + 2 * 16 * 136;
    unsigned short* vtile = lt + 16 * 200;
    const int w = tid >> 6;
    const int lane = tid & 63;
    const int quad = lane >> 4;
    const int l16 = lane & 15;
    const int m0 = bid * 16;
    const int b = m0 >> 11;
    const int srow = tid >> 4;
    const int sc = tid & 15;

    float4 ld[2];
    const float* xbase = x + (size_t)(m0 + srow) * 1024 + sc * 4;
    unsigned short* lxs[2] = {lx0, lx1};

#define LOAD_CHUNK(c)                               \
    {                                               \
        const float* p_ = xbase + (c) * 128;        \
        ld[0] = *(const float4*)(p_);               \
        ld[1] = *(const float4*)(p_ + 64);          \
    }
#define WRITE_CHUNK(buf)                                              \
    {                                                                 \
        unsigned short* p_ = lxs[buf] + srow * 136 + sc * 4;          \
        BF4 b0_, b1_;                                                 \
        b0_.s[0] = f2bf(ld[0].x); b0_.s[1] = f2bf(ld[0].y);           \
        b0_.s[2] = f2bf(ld[0].z); b0_.s[3] = f2bf(ld[0].w);           \
        b1_.s[0] = f2bf(ld[1].x); b1_.s[1] = f2bf(ld[1].y);           \
        b1_.s[2] = f2bf(ld[1].z); b1_.s[3] = f2bf(ld[1].w);           \
        *(unsigned long long*)(p_) = b0_.ull;                         \
        *(unsigned long long*)(p_ + 64) = b1_.ull;                    \
    }

    floatx4 acc[3];
#pragma unroll
    for (int i = 0; i < 3; ++i) acc[i] = (floatx4)(0.0f);

    LOAD_CHUNK(0);
    WRITE_CHUNK(0);
    __syncthreads();

    for (int c = 0; c < 8; ++c) {
        if (c < 7) LOAD_CHUNK(c + 1);
        const unsigned short* lp = lxs[c & 1] + l16 * 136 + quad * 8;
#pragma unroll
        for (int kst = 0; kst < 4; ++kst) {
            BF8 a;
            a.u = *(const uint4*)(lp + kst * 32);
            const int koct = c * 16 + kst * 4 + quad;
#pragma unroll
            for (int nt = 0; nt < 3; ++nt) {
                const int nb = w * 3 + nt;
                BF8 bfr;
                bfr.u = *(const uint4*)(wtf + ((size_t)nb * 128 + koct) * 128 + l16 * 8);
                acc[nt] = __builtin_amdgcn_mfma_f32_16x16x32_bf16(a.v, bfr.v, acc[nt], 0, 0, 0);
            }
        }
        if (c < 7) WRITE_CHUNK((c + 1) & 1);
        __syncthreads();
    }

#pragma unroll
    for (int nt = 0; nt < 3; ++nt) {
        const int ngl = w * 48 + nt * 16;
        if (ngl < 128) {
#pragma unroll
            for (int r = 0; r < 4; ++r)
                lt[(quad * 4 + r) * 200 + ngl + l16] = f2bf(acc[nt][r]);
        } else {
            BF4 pk;
#pragma unroll
            for (int r = 0; r < 4; ++r) pk.s[r] = f2bf(acc[nt][r]);
            *(unsigned long long*)&vtile[(ngl - 128 + l16) * 24 + quad * 4] = pk.ull;
        }
    }
    __syncthreads();

    {
        const int row = tid & 15;
        const int koct = tid >> 4;
        uint4 seg = *(const uint4*)&lt[row * 200 + koct * 8];
        const size_t tile = bid;
        if (koct < 8)
            *(uint4*)(qf + tile * 1024 + koct * 128 + row * 8) = seg;
        else
            *(uint4*)(kf + tile * 1024 + (koct - 8) * 128 + row * 8) = seg;
    }
    if (tid < 128) {
        const int h = tid >> 1;
        const int sg = tid & 1;
        uint4 seg = *(const uint4*)&vtile[h * 24 + sg * 8];
        const int jt = (m0 & 2047) >> 6;
        const int koct = ((m0 & 63) >> 3) + sg;
        *(uint4*)(vf + (((size_t)(b * 32 + jt) * 4 + (h >> 4)) * 8 + koct) * 128 +
                  (h & 15) * 8) = seg;
    }
#undef LOAD_CHUNK
#undef WRITE_CHUNK
}

__device__ __forceinline__ void phase_attn(int vb, int tid, unsigned short* smem,
                                           const unsigned short* qf,
                                           const unsigned short* kf,
                                           const unsigned short* vf,
                                           unsigned short* Opart, float* mpart,
                                           float* lpart) {
    const int w = tid >> 6;
    const int lane = tid & 63;
    const int quad = lane >> 4;
    const int l16 = lane & 15;
    unsigned short* myp = smem + w * (16 * 72);
    const int gid = vb * 4 + w;
    const int b = gid / 1088;
    const int rem = gid - b * 1088;
    int g = (int)((sqrtf((float)(4 * rem + 1)) - 1.0f) * 0.5f);
    while (4 * (g + 1) * (g + 2) <= rem) ++g;
    while (4 * g * (g + 1) > rem) --g;
    const int off = rem - 4 * g * (g + 1);
    const int nc = g + 1;
    const int qti = off / nc;
    const int kc = off - qti * nc;
    const int qt = g * 8 + qti;
    const int r0 = qt * 16;

    BF8 aq[2];
    {
        const unsigned short* qtile = qf + (size_t)(b * 128 + qt) * 1024;
        aq[0].u = *(const uint4*)(qtile + lane * 8);
        aq[1].u = *(const uint4*)(qtile + 512 + lane * 8);
    }

    floatx4 oacc[4];
#pragma unroll
    for (int nt = 0; nt < 4; ++nt) oacc[nt] = (floatx4)(0.0f);
    float m_i[4], l_i[4];
#pragma unroll
    for (int r = 0; r < 4; ++r) { m_i[r] = -3.0e38f; l_i[r] = 0.0f; }

    for (int t = 0; t < 2; ++t) {
        const int j0 = kc * 128 + t * 64;
        if (j0 > r0 + 15) break;

        floatx4 s[4];
#pragma unroll
        for (int nt = 0; nt < 4; ++nt) s[nt] = (floatx4)(0.0f);
#pragma unroll
        for (int kst = 0; kst < 2; ++kst) {
#pragma unroll
            for (int nt = 0; nt < 4; ++nt) {
                BF8 bk;
                bk.u = *(const uint4*)(kf + (size_t)(b * 128 + (j0 >> 4) + nt) * 1024 +
                                       kst * 512 + lane * 8);
                s[nt] = __builtin_amdgcn_mfma_f32_16x16x32_bf16(aq[kst].v, bk.v, s[nt], 0, 0, 0);
            }
        }

        float sv[4][4];
        const bool masked = (j0 + 63 > r0);
#pragma unroll
        for (int nt = 0; nt < 4; ++nt)
#pragma unroll
            for (int r = 0; r < 4; ++r) {
                float val = s[nt][r] * 0.125f;
                if (masked) {
                    int key = j0 + nt * 16 + l16;
                    int qr = r0 + quad * 4 + r;
                    if (key > qr) val = -3.0e38f;
                }
                sv[nt][r] = val;
            }

        float alpha[4];
#pragma unroll
        for (int r = 0; r < 4; ++r) {
            float mx = fmaxf(fmaxf(sv[0][r], sv[1][r]), fmaxf(sv[2][r], sv[3][r]));
            mx = fmaxf(mx, __shfl_xor(mx, 1));
            mx = fmaxf(mx, __shfl_xor(mx, 2));
            mx = fmaxf(mx, __shfl_xor(mx, 4));
            mx = fmaxf(mx, __shfl_xor(mx, 8));
            float mn = fmaxf(m_i[r], mx);
            alpha[r] = __expf(m_i[r] - mn);
            m_i[r] = mn;
        }
        float rs[4] = {0.f, 0.f, 0.f, 0.f};
#pragma unroll
        for (int nt = 0; nt < 4; ++nt)
#pragma unroll
            for (int r = 0; r < 4; ++r) {
                float p = __expf(sv[nt][r] - m_i[r]);
                sv[nt][r] = p;
                rs[r] += p;
            }
#pragma unroll
        for (int r = 0; r < 4; ++r) {
            float t2 = rs[r];
            t2 += __shfl_xor(t2, 1);
            t2 += __shfl_xor(t2, 2);
            t2 += __shfl_xor(t2, 4);
            t2 += __shfl_xor(t2, 8);
            l_i[r] = l_i[r] * alpha[r] + t2;
        }
#pragma unroll
        for (int nt = 0; nt < 4; ++nt)
#pragma unroll
            for (int r = 0; r < 4; ++r) oacc[nt][r] *= alpha[r];

#pragma unroll
        for (int nt = 0; nt < 4; ++nt)
#pragma unroll
            for (int r = 0; r < 4; ++r)
                myp[(quad * 4 + r) * 72 + nt * 16 + l16] = f2bf(sv[nt][r]);

#pragma unroll
        for (int kst = 0; kst < 2; ++kst) {
            BF8 ap;
            ap.u = *(const uint4*)(myp + l16 * 72 + kst * 32 + quad * 8);
#pragma unroll
            for (int nt = 0; nt < 4; ++nt) {
                BF8 bv;
                bv.u = *(const uint4*)(vf + ((size_t)(b * 32 + (j0 >> 6)) * 4 + nt) * 1024 +
                                       kst * 512 + lane * 8);
                oacc[nt] = __builtin_amdgcn_mfma_f32_16x16x32_bf16(ap.v, bv.v, oacc[nt], 0, 0, 0);
            }
        }
    }

    const size_t ob = (size_t)gid * 1024;
#pragma unroll
    for (int nt = 0; nt < 4; ++nt)
#pragma unroll
        for (int r = 0; r < 4; ++r)
            Opart[ob + (quad * 4 + r) * 64 + nt * 16 + l16] = f2bf(oacc[nt][r]);
    if (l16 == 0) {
#pragma unroll
        for (int r = 0; r < 4; ++r) {
            mpart[gid * 16 + quad * 4 + r] = m_i[r];
            lpart[gid * 16 + quad * 4 + r] = l_i[r];
        }
    }
}

__device__ __forceinline__ void phase_merge(int e, const unsigned short* Opart,
                                            const float* mpart, const float* lpart,
                                            float* out) {
    const int col = e & 63;
    const int t = (e >> 6) & 2047;
    const int b = e >> 17;
    const int qt = t >> 4;
    const int row16 = t & 15;
    const int g = qt >> 3;
    const int nc = g + 1;
    const int base_id = b * 1088 + 4 * g * (g + 1) + (qt & 7) * nc;

    float M = -3.0e38f, L = 0.0f, O = 0.0f;
#pragma unroll 4
    for (int c = 0; c < nc; ++c) {
        const float m_c = mpart[(base_id + c) * 16 + row16];
        const float l_c = lpart[(base_id + c) * 16 + row16];
        const float o_c = bf2f(Opart[(size_t)(base_id + c) * 1024 + row16 * 64 + col]);
        const float Mn = fmaxf(M, m_c);
        const float a = __expf(M - Mn);
        const float ec = __expf(m_c - Mn);
        L = L * a + ec * l_c;
        O = O * a + ec * o_c;
        M = Mn;
    }
    out[e] = O / L;
}

// ========================= fused cooperative kernel =========================
__global__ __launch_bounds__(256, 2) void mega_kernel(
    const float* __restrict__ x, const float* __restrict__ Wq,
    const float* __restrict__ Wk, const float* __restrict__ Wv,
    unsigned short* __restrict__ wtf, unsigned short* __restrict__ qf,
    unsigned short* __restrict__ kf, unsigned short* __restrict__ vf,
    unsigned short* __restrict__ Opart, float* __restrict__ mpart,
    float* __restrict__ lpart, float* __restrict__ out) {
    cg::grid_group grid = cg::this_grid();
    __shared__ __align__(16) unsigned short smem[9088];
    const int tid = threadIdx.x;
    const int bid = blockIdx.x;

    if (bid < 48) phase_wtf(bid, tid, smem, Wq, Wk, Wv, wtf);
    __threadfence();
    grid.sync();

    phase_qkv(bid, tid, smem, x, wtf, qf, kf, vf);
    __threadfence();
    grid.sync();

    for (int it = 0; it < 3; ++it) {
        const int vb = bid + it * 512;
        if (vb >= 1088) break;
        phase_attn(vb, tid, smem, qf, kf, vf, Opart, mpart, lpart);
    }
    __threadfence();
    grid.sync();

#pragma unroll
    for (int it = 0; it < 4; ++it)
        phase_merge((bid + it * 512) * 256 + tid, Opart, mpart, lpart, out);
}

// ========================= standalone fallback kernels =========================
__global__ __launch_bounds__(256) void wt_kernel(const float* __restrict__ Wq,
                                                 const float* __restrict__ Wk,
                                                 const float* __restrict__ Wv,
                                                 unsigned short* __restrict__ wtf) {
    __shared__ __align__(16) unsigned short lt[64 * 72];
    phase_wtf(blockIdx.x, threadIdx.x, lt, Wq, Wk, Wv, wtf);
}

__global__ __launch_bounds__(256) void qkv_kernel(const float* __restrict__ x,
                                                  const unsigned short* __restrict__ wtf,
                                                  unsigned short* __restrict__ qf,
                                                  unsigned short* __restrict__ kf,
                                                  unsigned short* __restrict__ vf) {
    __shared__ __align__(16) unsigned short smem[9088];
    phase_qkv(blockIdx.x, threadIdx.x, smem, x, wtf, qf, kf, vf);
}

__global__ __launch_bounds__(256) void attn_partial(const unsigned short* __restrict__ qf,
                                                    const unsigned short* __restrict__ kf,
                                                    const unsigned short* __restrict__ vf,
                                                    unsigned short* __restrict__ Opart,
                                                    float* __restrict__ mpart,
                                                    float* __restrict__ lpart) {
    __shared__ __align__(16) unsigned short smem[4 * 16 * 72];
    phase_attn(blockIdx.x, threadIdx.x, smem, qf, kf, vf, Opart, mpart, lpart);
}

__global__ __launch_bounds__(256) void attn_merge(const unsigned short* __restrict__ Opart,
                                                  const float* __restrict__ mpart,
                                                  const float* __restrict__ lpart,
                                                  float* __restrict__ out) {
    phase_merge(blockIdx.x * 256 + threadIdx.x, Opart, mpart, lpart, out);
}

extern "C" void kernel_launch(void* const* d_in, const int* in_sizes, int n_in,
                              void* d_out, int out_size, void* d_ws, size_t ws_size,
                              hipStream_t stream) {
    const float* x = (const float*)d_in[0];
    const float* Wq = (const float*)d_in[1];
    const float* Wk = (const float*)d_in[2];
    const float* Wv = (const float*)d_in[3];
    float* out = (float*)d_out;

    char* ws = (char*)d_ws;
    unsigned short* wtf = (unsigned short*)(ws);
    unsigned short* qf = (unsigned short*)(ws + 393216);
    unsigned short* kf = (unsigned short*)(ws + 1441792);
    unsigned short* vf = (unsigned short*)(ws + 2490368);
    unsigned short* Opart = (unsigned short*)(ws + 3538944);
    float* mpart = (float*)(ws + 12451840ull);
    float* lpart = (float*)(ws + 12730368ull);

    void* args[] = {&x, &Wq, &Wk, &Wv, &wtf, &qf, &kf, &vf, &Opart, &mpart, &lpart, &out};
    hipError_t err = hipLaunchCooperativeKernel((void*)mega_kernel, dim3(512), dim3(256),
                                                args, 0, stream);
    if (err != hipSuccess) {
        // fallback: R9 4-launch path (known-good, ~106us)
        hipLaunchKernelGGL(wt_kernel, dim3(48), dim3(256), 0, stream, Wq, Wk, Wv, wtf);
        hipLaunchKernelGGL(qkv_kernel, dim3(512), dim3(256), 0, stream, x, wtf, qf, kf, vf);
        hipLaunchKernelGGL(attn_partial, dim3(1088), dim3(256), 0, stream, qf, kf, vf,
                           Opart, mpart, lpart);
        hipLaunchKernelGGL(attn_merge, dim3(2048), dim3(256), 0, stream, Opart, mpart,
                           lpart, out);
    }
}

// Round 13
// 280.580 us; speedup vs baseline: 1.5667x; 1.5667x over previous
//
#include <hip/hip_runtime.h>

// Head: single-head causal attention. B=4, T=2048, D=1024, H=64. fp32 in/out.
// R13: revert R12's coop fusion (grid.sync ~100us/sync on ROCm -> 367us).
// Back to R9's 4-phase structure, but merge is FUSED into attn_partial via
// stream-K last-arriver pattern: after partial write, __threadfence +
// atomicAdd(cnt[b,qt]); the wave completing the count merges in-register
// (16 rows / 48 VGPRs, L2-warm partials) and writes out. 3 launches total.
//
// ws layout (bytes):
//   [0,        393216)   wtf   bf16 [12][128][16][8]   (fragment-ordered W)
//   [393216,  1441792)   qf    bf16 [512][8][16][8]
//   [1441792, 2490368)   kf    bf16 [512][8][16][8]
//   [2490368, 3538944)   vf    bf16 [4][32][4][8][16][8]
//   [3538944, 12451840)  Opart bf16 [4352][16][64]     (gid-indexed)
//   [12451840,12730368)  mpart fp32 [4352][16]
//   [12730368,13008896)  lpart fp32 [4352][16]
//   [13008896,13010944)  cnt   int  [512]              (zeroed each launch)

typedef __attribute__((ext_vector_type(8))) __bf16 bf16x8;
typedef __attribute__((ext_vector_type(4))) float floatx4;

union BF8 {
    bf16x8 v;
    unsigned short s[8];
    uint4 u;
};
union BF4 {
    unsigned short s[4];
    unsigned long long ull;
};

__device__ inline unsigned short f2bf(float f) {
    unsigned int u = __float_as_uint(f);
    unsigned int r = (u + 0x7fffu + ((u >> 16) & 1u)) >> 16;
    return (unsigned short)r;
}
__device__ inline float bf2f(unsigned short s) {
    unsigned int u = ((unsigned int)s) << 16;
    return __uint_as_float(u);
}

// ---------------------------------------------------------------------------
// Kernel 0: W -> wtf fragment layout (R9 verbatim). Grid 48 = 3 x 16.
// ---------------------------------------------------------------------------
__global__ __launch_bounds__(256) void wt_kernel(const float* __restrict__ Wq,
                                                 const float* __restrict__ Wk,
                                                 const float* __restrict__ Wv,
                                                 unsigned short* __restrict__ wtf) {
    __shared__ __align__(16) unsigned short lt[64 * 72];
    const int tid = threadIdx.x;
    const int sel = blockIdx.x >> 4;
    const int kb = blockIdx.x & 15;
    const float* W = (sel == 0) ? Wq : (sel == 1) ? Wk : Wv;

    const int h = tid & 63;
    const int kr = tid >> 6;
#pragma unroll
    for (int i = 0; i < 16; ++i) {
        const int kkl = kr + i * 4;
        lt[kkl * 72 + h] = f2bf(W[(size_t)(kb * 64 + kkl) * 64 + h]);
    }
    __syncthreads();

#pragma unroll
    for (int s = 0; s < 2; ++s) {
        const int seg = tid + s * 256;
        const int l16 = seg & 15;
        const int rest = seg >> 4;
        const int ko = rest & 7;
        const int hb = rest >> 3;
        const int hh = hb * 16 + l16;
        BF8 o;
#pragma unroll
        for (int j = 0; j < 8; ++j) o.s[j] = lt[(ko * 8 + j) * 72 + hh];
        const int nblk = sel * 4 + hb;
        const int koct = kb * 8 + ko;
        *(uint4*)(wtf + ((size_t)nblk * 128 + koct) * 128 + l16 * 8) = o.u;
    }
}

// ---------------------------------------------------------------------------
// Kernel 1: QKV projection (R9 verbatim). Grid 512 x 256.
// ---------------------------------------------------------------------------
__global__ __launch_bounds__(256) void qkv_kernel(const float* __restrict__ x,
                                                  const unsigned short* __restrict__ wtf,
                                                  unsigned short* __restrict__ qf,
                                                  unsigned short* __restrict__ kf,
                                                  unsigned short* __restrict__ vf) {
    __shared__ __align__(16) unsigned short lx[2][16 * 136];
    __shared__ __align__(16) unsigned short lt[16 * 200];
    __shared__ __align__(16) unsigned short vtile[64 * 24];
    const int tid = threadIdx.x;
    const int w = tid >> 6;
    const int lane = tid & 63;
    const int quad = lane >> 4;
    const int l16 = lane & 15;
    const int m0 = blockIdx.x * 16;
    const int b = m0 >> 11;
    const int srow = tid >> 4;
    const int sc = tid & 15;

    float4 ld[2];
    const float* xbase = x + (size_t)(m0 + srow) * 1024 + sc * 4;

#define LOAD_CHUNK(c)                               \
    {                                               \
        const float* p_ = xbase + (c) * 128;        \
        ld[0] = *(const float4*)(p_);               \
        ld[1] = *(const float4*)(p_ + 64);          \
    }
#define WRITE_CHUNK(buf)                                              \
    {                                                                 \
        unsigned short* p_ = &lx[buf][0] + srow * 136 + sc * 4;       \
        BF4 b0_, b1_;                                                 \
        b0_.s[0] = f2bf(ld[0].x); b0_.s[1] = f2bf(ld[0].y);           \
        b0_.s[2] = f2bf(ld[0].z); b0_.s[3] = f2bf(ld[0].w);           \
        b1_.s[0] = f2bf(ld[1].x); b1_.s[1] = f2bf(ld[1].y);           \
        b1_.s[2] = f2bf(ld[1].z); b1_.s[3] = f2bf(ld[1].w);           \
        *(unsigned long long*)(p_) = b0_.ull;                         \
        *(unsigned long long*)(p_ + 64) = b1_.ull;                    \
    }

    floatx4 acc[3];
#pragma unroll
    for (int i = 0; i < 3; ++i) acc[i] = (floatx4)(0.0f);

    LOAD_CHUNK(0);
    WRITE_CHUNK(0);
    __syncthreads();

    for (int c = 0; c < 8; ++c) {
        if (c < 7) LOAD_CHUNK(c + 1);
        const unsigned short* lp = &lx[c & 1][0] + l16 * 136 + quad * 8;
#pragma unroll
        for (int kst = 0; kst < 4; ++kst) {
            BF8 a;
            a.u = *(const uint4*)(lp + kst * 32);
            const int koct = c * 16 + kst * 4 + quad;
#pragma unroll
            for (int nt = 0; nt < 3; ++nt) {
                const int nb = w * 3 + nt;
                BF8 bfr;
                bfr.u = *(const uint4*)(wtf + ((size_t)nb * 128 + koct) * 128 + l16 * 8);
                acc[nt] = __builtin_amdgcn_mfma_f32_16x16x32_bf16(a.v, bfr.v, acc[nt], 0, 0, 0);
            }
        }
        if (c < 7) WRITE_CHUNK((c + 1) & 1);
        __syncthreads();
    }

#pragma unroll
    for (int nt = 0; nt < 3; ++nt) {
        const int ngl = w * 48 + nt * 16;
        if (ngl < 128) {
#pragma unroll
            for (int r = 0; r < 4; ++r)
                lt[(quad * 4 + r) * 200 + ngl + l16] = f2bf(acc[nt][r]);
        } else {
            BF4 pk;
#pragma unroll
            for (int r = 0; r < 4; ++r) pk.s[r] = f2bf(acc[nt][r]);
            *(unsigned long long*)&vtile[(ngl - 128 + l16) * 24 + quad * 4] = pk.ull;
        }
    }
    __syncthreads();

    {
        const int row = tid & 15;
        const int koct = tid >> 4;
        uint4 seg = *(const uint4*)&lt[row * 200 + koct * 8];
        const size_t tile = blockIdx.x;
        if (koct < 8)
            *(uint4*)(qf + tile * 1024 + koct * 128 + row * 8) = seg;
        else
            *(uint4*)(kf + tile * 1024 + (koct - 8) * 128 + row * 8) = seg;
    }
    if (tid < 128) {
        const int h = tid >> 1;
        const int sg = tid & 1;
        uint4 seg = *(const uint4*)&vtile[h * 24 + sg * 8];
        const int jt = (m0 & 2047) >> 6;
        const int koct = ((m0 & 63) >> 3) + sg;
        *(uint4*)(vf + (((size_t)(b * 32 + jt) * 4 + (h >> 4)) * 8 + koct) * 128 +
                  (h & 15) * 8) = seg;
    }
#undef LOAD_CHUNK
#undef WRITE_CHUNK
}

// ---------------------------------------------------------------------------
// Kernel 2: flash pass A + fused stream-K merge. Grid 1088 x 4 waves = 4352
// gids (triangular, all active). After partial write: threadfence +
// atomicAdd(cnt[b*128+qt]); last arriver (count==nc) merges all nc partials
// for that q-tile in-register and writes the final output rows.
// ---------------------------------------------------------------------------
__global__ __launch_bounds__(256) void attn_partial(const unsigned short* __restrict__ qf,
                                                    const unsigned short* __restrict__ kf,
                                                    const unsigned short* __restrict__ vf,
                                                    unsigned short* __restrict__ Opart,
                                                    float* __restrict__ mpart,
                                                    float* __restrict__ lpart,
                                                    int* __restrict__ cnt,
                                                    float* __restrict__ out) {
    __shared__ __align__(16) unsigned short lds_p[4 * 16 * 72];
    const int tid = threadIdx.x;
    const int w = tid >> 6;
    const int lane = tid & 63;
    const int quad = lane >> 4;
    const int l16 = lane & 15;
    const int gid = blockIdx.x * 4 + w;  // 0..4351
    const int b = gid / 1088;
    const int rem = gid - b * 1088;
    int g = (int)((sqrtf((float)(4 * rem + 1)) - 1.0f) * 0.5f);
    while (4 * (g + 1) * (g + 2) <= rem) ++g;
    while (4 * g * (g + 1) > rem) --g;
    const int off = rem - 4 * g * (g + 1);
    const int nc = g + 1;
    const int qti = off / nc;
    const int kc = off - qti * nc;
    const int qt = g * 8 + qti;
    const int r0 = qt * 16;

    BF8 aq[2];
    {
        const unsigned short* qtile = qf + (size_t)(b * 128 + qt) * 1024;
        aq[0].u = *(const uint4*)(qtile + lane * 8);
        aq[1].u = *(const uint4*)(qtile + 512 + lane * 8);
    }

    floatx4 oacc[4];
#pragma unroll
    for (int nt = 0; nt < 4; ++nt) oacc[nt] = (floatx4)(0.0f);
    float m_i[4], l_i[4];
#pragma unroll
    for (int r = 0; r < 4; ++r) { m_i[r] = -3.0e38f; l_i[r] = 0.0f; }

    unsigned short* myp = lds_p + w * (16 * 72);

    for (int t = 0; t < 2; ++t) {
        const int j0 = kc * 128 + t * 64;
        if (j0 > r0 + 15) break;

        floatx4 s[4];
#pragma unroll
        for (int nt = 0; nt < 4; ++nt) s[nt] = (floatx4)(0.0f);
#pragma unroll
        for (int kst = 0; kst < 2; ++kst) {
#pragma unroll
            for (int nt = 0; nt < 4; ++nt) {
                BF8 bk;
                bk.u = *(const uint4*)(kf + (size_t)(b * 128 + (j0 >> 4) + nt) * 1024 +
                                       kst * 512 + lane * 8);
                s[nt] = __builtin_amdgcn_mfma_f32_16x16x32_bf16(aq[kst].v, bk.v, s[nt], 0, 0, 0);
            }
        }

        float sv[4][4];
        const bool masked = (j0 + 63 > r0);
#pragma unroll
        for (int nt = 0; nt < 4; ++nt)
#pragma unroll
            for (int r = 0; r < 4; ++r) {
                float val = s[nt][r] * 0.125f;
                if (masked) {
                    int key = j0 + nt * 16 + l16;
                    int qr = r0 + quad * 4 + r;
                    if (key > qr) val = -3.0e38f;
                }
                sv[nt][r] = val;
            }

        float alpha[4];
#pragma unroll
        for (int r = 0; r < 4; ++r) {
            float mx = fmaxf(fmaxf(sv[0][r], sv[1][r]), fmaxf(sv[2][r], sv[3][r]));
            mx = fmaxf(mx, __shfl_xor(mx, 1));
            mx = fmaxf(mx, __shfl_xor(mx, 2));
            mx = fmaxf(mx, __shfl_xor(mx, 4));
            mx = fmaxf(mx, __shfl_xor(mx, 8));
            float mn = fmaxf(m_i[r], mx);
            alpha[r] = __expf(m_i[r] - mn);
            m_i[r] = mn;
        }
        float rs[4] = {0.f, 0.f, 0.f, 0.f};
#pragma unroll
        for (int nt = 0; nt < 4; ++nt)
#pragma unroll
            for (int r = 0; r < 4; ++r) {
                float p = __expf(sv[nt][r] - m_i[r]);
                sv[nt][r] = p;
                rs[r] += p;
            }
#pragma unroll
        for (int r = 0; r < 4; ++r) {
            float t2 = rs[r];
            t2 += __shfl_xor(t2, 1);
            t2 += __shfl_xor(t2, 2);
            t2 += __shfl_xor(t2, 4);
            t2 += __shfl_xor(t2, 8);
            l_i[r] = l_i[r] * alpha[r] + t2;
        }
#pragma unroll
        for (int nt = 0; nt < 4; ++nt)
#pragma unroll
            for (int r = 0; r < 4; ++r) oacc[nt][r] *= alpha[r];

#pragma unroll
        for (int nt = 0; nt < 4; ++nt)
#pragma unroll
            for (int r = 0; r < 4; ++r)
                myp[(quad * 4 + r) * 72 + nt * 16 + l16] = f2bf(sv[nt][r]);

#pragma unroll
        for (int kst = 0; kst < 2; ++kst) {
            BF8 ap;
            ap.u = *(const uint4*)(myp + l16 * 72 + kst * 32 + quad * 8);
#pragma unroll
            for (int nt = 0; nt < 4; ++nt) {
                BF8 bv;
                bv.u = *(const uint4*)(vf + ((size_t)(b * 32 + (j0 >> 6)) * 4 + nt) * 1024 +
                                       kst * 512 + lane * 8);
                oacc[nt] = __builtin_amdgcn_mfma_f32_16x16x32_bf16(ap.v, bv.v, oacc[nt], 0, 0, 0);
            }
        }
    }

    const size_t ob = (size_t)gid * 1024;
#pragma unroll
    for (int nt = 0; nt < 4; ++nt)
#pragma unroll
        for (int r = 0; r < 4; ++r)
            Opart[ob + (quad * 4 + r) * 64 + nt * 16 + l16] = f2bf(oacc[nt][r]);
    if (l16 == 0) {
#pragma unroll
        for (int r = 0; r < 4; ++r) {
            mpart[gid * 16 + quad * 4 + r] = m_i[r];
            lpart[gid * 16 + quad * 4 + r] = l_i[r];
        }
    }

    // ---- stream-K last-arriver merge ----
    __threadfence();  // make partials visible device-wide before signaling
    int old = 0;
    if (lane == 0) old = atomicAdd(&cnt[b * 128 + qt], 1);
    old = __shfl(old, 0);
    if (old != nc - 1) return;
    __threadfence();  // acquire: invalidate L1 before reading others' partials

    const int base_id = b * 1088 + 4 * g * (g + 1) + qti * nc;
    float M[16], L[16], O[16];
#pragma unroll
    for (int r = 0; r < 16; ++r) { M[r] = -3.0e38f; L[r] = 0.0f; O[r] = 0.0f; }
    for (int c = 0; c < nc; ++c) {
        const float* mp = mpart + (size_t)(base_id + c) * 16;
        const float* lp = lpart + (size_t)(base_id + c) * 16;
        const unsigned short* op = Opart + (size_t)(base_id + c) * 1024 + lane;
#pragma unroll
        for (int r = 0; r < 16; ++r) {
            const float m_c = mp[r];
            const float l_c = lp[r];
            const float o_c = bf2f(op[r * 64]);
            const float Mn = fmaxf(M[r], m_c);
            const float a = __expf(M[r] - Mn);
            const float ec = __expf(m_c - Mn);
            L[r] = L[r] * a + ec * l_c;
            O[r] = O[r] * a + ec * o_c;
            M[r] = Mn;
        }
    }
    float* outp = out + (size_t)(b * 2048 + qt * 16) * 64 + lane;
#pragma unroll
    for (int r = 0; r < 16; ++r) outp[r * 64] = O[r] / L[r];
}

extern "C" void kernel_launch(void* const* d_in, const int* in_sizes, int n_in,
                              void* d_out, int out_size, void* d_ws, size_t ws_size,
                              hipStream_t stream) {
    const float* x = (const float*)d_in[0];
    const float* Wq = (const float*)d_in[1];
    const float* Wk = (const float*)d_in[2];
    const float* Wv = (const float*)d_in[3];
    float* out = (float*)d_out;

    char* ws = (char*)d_ws;
    unsigned short* wtf = (unsigned short*)(ws);
    unsigned short* qf = (unsigned short*)(ws + 393216);
    unsigned short* kf = (unsigned short*)(ws + 1441792);
    unsigned short* vf = (unsigned short*)(ws + 2490368);
    unsigned short* Opart = (unsigned short*)(ws + 3538944);
    float* mpart = (float*)(ws + 12451840ull);
    float* lpart = (float*)(ws + 12730368ull);
    int* cnt = (int*)(ws + 13008896ull);

    hipMemsetAsync(cnt, 0, 512 * sizeof(int), stream);
    hipLaunchKernelGGL(wt_kernel, dim3(48), dim3(256), 0, stream, Wq, Wk, Wv, wtf);
    hipLaunchKernelGGL(qkv_kernel, dim3(512), dim3(256), 0, stream, x, wtf, qf, kf, vf);
    hipLaunchKernelGGL(attn_partial, dim3(1088), dim3(256), 0, stream, qf, kf, vf,
                       Opart, mpart, lpart, cnt, out);
}

// Round 14
// 117.594 us; speedup vs baseline: 3.7382x; 2.3860x over previous
//
#include <hip/hip_runtime.h>

// Head: single-head causal attention. B=4, T=2048, D=1024, H=64. fp32 in/out.
// R14: R12 (grid.sync ~100us each) and R13 (per-wave __threadfence -> L2
// writeback storm on 8 non-coherent XCD L2s, 202us) both falsified device-
// scope sync. Merge now happens INSIDE one block via LDS (__syncthreads is
// CU-local): grid 512 = (b,qt); wave w owns K-tiles t=w,w+4,.. (<=8 serial,
// avg 4); block epilogue merges the 4 online-softmax chains per row and
// writes out directly. No Opart/mpart/lpart, no merge kernel, 3 launches.
// wt/qkv verbatim R9 (the 106us config).
//
// ws layout (bytes):
//   [0,        393216)   wtf   bf16 [12][128][16][8]   (fragment-ordered W)
//   [393216,  1441792)   qf    bf16 [512][8][16][8]
//   [1441792, 2490368)   kf    bf16 [512][8][16][8]
//   [2490368, 3538944)   vf    bf16 [4][32][4][8][16][8]

typedef __attribute__((ext_vector_type(8))) __bf16 bf16x8;
typedef __attribute__((ext_vector_type(4))) float floatx4;

union BF8 {
    bf16x8 v;
    unsigned short s[8];
    uint4 u;
};
union BF4 {
    unsigned short s[4];
    unsigned long long ull;
};

__device__ inline unsigned short f2bf(float f) {
    unsigned int u = __float_as_uint(f);
    unsigned int r = (u + 0x7fffu + ((u >> 16) & 1u)) >> 16;
    return (unsigned short)r;
}

// ---------------------------------------------------------------------------
// Kernel 0: W -> wtf fragment layout (R9 verbatim). Grid 48 = 3 x 16.
// ---------------------------------------------------------------------------
__global__ __launch_bounds__(256) void wt_kernel(const float* __restrict__ Wq,
                                                 const float* __restrict__ Wk,
                                                 const float* __restrict__ Wv,
                                                 unsigned short* __restrict__ wtf) {
    __shared__ __align__(16) unsigned short lt[64 * 72];
    const int tid = threadIdx.x;
    const int sel = blockIdx.x >> 4;
    const int kb = blockIdx.x & 15;
    const float* W = (sel == 0) ? Wq : (sel == 1) ? Wk : Wv;

    const int h = tid & 63;
    const int kr = tid >> 6;
#pragma unroll
    for (int i = 0; i < 16; ++i) {
        const int kkl = kr + i * 4;
        lt[kkl * 72 + h] = f2bf(W[(size_t)(kb * 64 + kkl) * 64 + h]);
    }
    __syncthreads();

#pragma unroll
    for (int s = 0; s < 2; ++s) {
        const int seg = tid + s * 256;
        const int l16 = seg & 15;
        const int rest = seg >> 4;
        const int ko = rest & 7;
        const int hb = rest >> 3;
        const int hh = hb * 16 + l16;
        BF8 o;
#pragma unroll
        for (int j = 0; j < 8; ++j) o.s[j] = lt[(ko * 8 + j) * 72 + hh];
        const int nblk = sel * 4 + hb;
        const int koct = kb * 8 + ko;
        *(uint4*)(wtf + ((size_t)nblk * 128 + koct) * 128 + l16 * 8) = o.u;
    }
}

// ---------------------------------------------------------------------------
// Kernel 1: QKV projection (R9 verbatim). Grid 512 x 256.
// ---------------------------------------------------------------------------
__global__ __launch_bounds__(256) void qkv_kernel(const float* __restrict__ x,
                                                  const unsigned short* __restrict__ wtf,
                                                  unsigned short* __restrict__ qf,
                                                  unsigned short* __restrict__ kf,
                                                  unsigned short* __restrict__ vf) {
    __shared__ __align__(16) unsigned short lx[2][16 * 136];
    __shared__ __align__(16) unsigned short lt[16 * 200];
    __shared__ __align__(16) unsigned short vtile[64 * 24];
    const int tid = threadIdx.x;
    const int w = tid >> 6;
    const int lane = tid & 63;
    const int quad = lane >> 4;
    const int l16 = lane & 15;
    const int m0 = blockIdx.x * 16;
    const int b = m0 >> 11;
    const int srow = tid >> 4;
    const int sc = tid & 15;

    float4 ld[2];
    const float* xbase = x + (size_t)(m0 + srow) * 1024 + sc * 4;

#define LOAD_CHUNK(c)                               \
    {                                               \
        const float* p_ = xbase + (c) * 128;        \
        ld[0] = *(const float4*)(p_);               \
        ld[1] = *(const float4*)(p_ + 64);          \
    }
#define WRITE_CHUNK(buf)                                              \
    {                                                                 \
        unsigned short* p_ = &lx[buf][0] + srow * 136 + sc * 4;       \
        BF4 b0_, b1_;                                                 \
        b0_.s[0] = f2bf(ld[0].x); b0_.s[1] = f2bf(ld[0].y);           \
        b0_.s[2] = f2bf(ld[0].z); b0_.s[3] = f2bf(ld[0].w);           \
        b1_.s[0] = f2bf(ld[1].x); b1_.s[1] = f2bf(ld[1].y);           \
        b1_.s[2] = f2bf(ld[1].z); b1_.s[3] = f2bf(ld[1].w);           \
        *(unsigned long long*)(p_) = b0_.ull;                         \
        *(unsigned long long*)(p_ + 64) = b1_.ull;                    \
    }

    floatx4 acc[3];
#pragma unroll
    for (int i = 0; i < 3; ++i) acc[i] = (floatx4)(0.0f);

    LOAD_CHUNK(0);
    WRITE_CHUNK(0);
    __syncthreads();

    for (int c = 0; c < 8; ++c) {
        if (c < 7) LOAD_CHUNK(c + 1);
        const unsigned short* lp = &lx[c & 1][0] + l16 * 136 + quad * 8;
#pragma unroll
        for (int kst = 0; kst < 4; ++kst) {
            BF8 a;
            a.u = *(const uint4*)(lp + kst * 32);
            const int koct = c * 16 + kst * 4 + quad;
#pragma unroll
            for (int nt = 0; nt < 3; ++nt) {
                const int nb = w * 3 + nt;
                BF8 bfr;
                bfr.u = *(const uint4*)(wtf + ((size_t)nb * 128 + koct) * 128 + l16 * 8);
                acc[nt] = __builtin_amdgcn_mfma_f32_16x16x32_bf16(a.v, bfr.v, acc[nt], 0, 0, 0);
            }
        }
        if (c < 7) WRITE_CHUNK((c + 1) & 1);
        __syncthreads();
    }

#pragma unroll
    for (int nt = 0; nt < 3; ++nt) {
        const int ngl = w * 48 + nt * 16;
        if (ngl < 128) {
#pragma unroll
            for (int r = 0; r < 4; ++r)
                lt[(quad * 4 + r) * 200 + ngl + l16] = f2bf(acc[nt][r]);
        } else {
            BF4 pk;
#pragma unroll
            for (int r = 0; r < 4; ++r) pk.s[r] = f2bf(acc[nt][r]);
            *(unsigned long long*)&vtile[(ngl - 128 + l16) * 24 + quad * 4] = pk.ull;
        }
    }
    __syncthreads();

    {
        const int row = tid & 15;
        const int koct = tid >> 4;
        uint4 seg = *(const uint4*)&lt[row * 200 + koct * 8];
        const size_t tile = blockIdx.x;
        if (koct < 8)
            *(uint4*)(qf + tile * 1024 + koct * 128 + row * 8) = seg;
        else
            *(uint4*)(kf + tile * 1024 + (koct - 8) * 128 + row * 8) = seg;
    }
    if (tid < 128) {
        const int h = tid >> 1;
        const int sg = tid & 1;
        uint4 seg = *(const uint4*)&vtile[h * 24 + sg * 8];
        const int jt = (m0 & 2047) >> 6;
        const int koct = ((m0 & 63) >> 3) + sg;
        *(uint4*)(vf + (((size_t)(b * 32 + jt) * 4 + (h >> 4)) * 8 + koct) * 128 +
                  (h & 15) * 8) = seg;
    }
#undef LOAD_CHUNK
#undef WRITE_CHUNK
}

// ---------------------------------------------------------------------------
// Kernel 2: flash attention, block = one q-tile. Grid 512 = (b<<7)|qt.
// Wave w owns K-tiles t = w, w+4, ... of ntiles = (qt>>2)+1 (<=8 serial,
// avg ~4). Per-wave online softmax (R9-verified inner body); 4 chains merged
// through LDS (fp32 O — more precise than R9's bf16 Opart), direct out write.
// No device-scope sync anywhere.
// ---------------------------------------------------------------------------
__global__ __launch_bounds__(256) void attn_kernel(const unsigned short* __restrict__ qf,
                                                   const unsigned short* __restrict__ kf,
                                                   const unsigned short* __restrict__ vf,
                                                   float* __restrict__ out) {
    __shared__ __align__(16) unsigned short lds_p[4 * 16 * 72];  // 9216 B
    __shared__ __align__(16) float lds_O[4 * 16 * 64];           // 16384 B
    __shared__ float lds_m[64], lds_l[64];                       // 512 B
    const int tid = threadIdx.x;
    const int w = tid >> 6;
    const int lane = tid & 63;
    const int quad = lane >> 4;
    const int l16 = lane & 15;
    const int b = blockIdx.x >> 7;
    const int qt = blockIdx.x & 127;
    const int r0 = qt * 16;
    const int ntiles = (qt >> 2) + 1;

    BF8 aq[2];
    {
        const unsigned short* qtile = qf + (size_t)(b * 128 + qt) * 1024;
        aq[0].u = *(const uint4*)(qtile + lane * 8);
        aq[1].u = *(const uint4*)(qtile + 512 + lane * 8);
    }

    floatx4 oacc[4];
#pragma unroll
    for (int nt = 0; nt < 4; ++nt) oacc[nt] = (floatx4)(0.0f);
    float m_i[4], l_i[4];
#pragma unroll
    for (int r = 0; r < 4; ++r) { m_i[r] = -3.0e38f; l_i[r] = 0.0f; }

    unsigned short* myp = lds_p + w * (16 * 72);

    for (int t = w; t < ntiles; t += 4) {
        const int j0 = t * 64;

        floatx4 s[4];
#pragma unroll
        for (int nt = 0; nt < 4; ++nt) s[nt] = (floatx4)(0.0f);
#pragma unroll
        for (int kst = 0; kst < 2; ++kst) {
#pragma unroll
            for (int nt = 0; nt < 4; ++nt) {
                BF8 bk;
                bk.u = *(const uint4*)(kf + (size_t)(b * 128 + (j0 >> 4) + nt) * 1024 +
                                       kst * 512 + lane * 8);
                s[nt] = __builtin_amdgcn_mfma_f32_16x16x32_bf16(aq[kst].v, bk.v, s[nt], 0, 0, 0);
            }
        }

        float sv[4][4];
        const bool masked = (j0 + 63 > r0);
#pragma unroll
        for (int nt = 0; nt < 4; ++nt)
#pragma unroll
            for (int r = 0; r < 4; ++r) {
                float val = s[nt][r] * 0.125f;
                if (masked) {
                    int key = j0 + nt * 16 + l16;
                    int qr = r0 + quad * 4 + r;
                    if (key > qr) val = -3.0e38f;
                }
                sv[nt][r] = val;
            }

        float alpha[4];
#pragma unroll
        for (int r = 0; r < 4; ++r) {
            float mx = fmaxf(fmaxf(sv[0][r], sv[1][r]), fmaxf(sv[2][r], sv[3][r]));
            mx = fmaxf(mx, __shfl_xor(mx, 1));
            mx = fmaxf(mx, __shfl_xor(mx, 2));
            mx = fmaxf(mx, __shfl_xor(mx, 4));
            mx = fmaxf(mx, __shfl_xor(mx, 8));
            float mn = fmaxf(m_i[r], mx);
            alpha[r] = __expf(m_i[r] - mn);
            m_i[r] = mn;
        }
        float rs[4] = {0.f, 0.f, 0.f, 0.f};
#pragma unroll
        for (int nt = 0; nt < 4; ++nt)
#pragma unroll
            for (int r = 0; r < 4; ++r) {
                float p = __expf(sv[nt][r] - m_i[r]);
                sv[nt][r] = p;
                rs[r] += p;
            }
#pragma unroll
        for (int r = 0; r < 4; ++r) {
            float t2 = rs[r];
            t2 += __shfl_xor(t2, 1);
            t2 += __shfl_xor(t2, 2);
            t2 += __shfl_xor(t2, 4);
            t2 += __shfl_xor(t2, 8);
            l_i[r] = l_i[r] * alpha[r] + t2;
        }
#pragma unroll
        for (int nt = 0; nt < 4; ++nt)
#pragma unroll
            for (int r = 0; r < 4; ++r) oacc[nt][r] *= alpha[r];

#pragma unroll
        for (int nt = 0; nt < 4; ++nt)
#pragma unroll
            for (int r = 0; r < 4; ++r)
                myp[(quad * 4 + r) * 72 + nt * 16 + l16] = f2bf(sv[nt][r]);

#pragma unroll
        for (int kst = 0; kst < 2; ++kst) {
            BF8 ap;
            ap.u = *(const uint4*)(myp + l16 * 72 + kst * 32 + quad * 8);
#pragma unroll
            for (int nt = 0; nt < 4; ++nt) {
                BF8 bv;
                bv.u = *(const uint4*)(vf + ((size_t)(b * 32 + (j0 >> 6)) * 4 + nt) * 1024 +
                                       kst * 512 + lane * 8);
                oacc[nt] = __builtin_amdgcn_mfma_f32_16x16x32_bf16(ap.v, bv.v, oacc[nt], 0, 0, 0);
            }
        }
    }

    // ---- block-level merge of the 4 wave chains (LDS, CU-local sync) ----
    if (l16 == 0) {
#pragma unroll
        for (int r = 0; r < 4; ++r) {
            lds_m[w * 16 + quad * 4 + r] = m_i[r];
            lds_l[w * 16 + quad * 4 + r] = l_i[r];
        }
    }
#pragma unroll
    for (int nt = 0; nt < 4; ++nt)
#pragma unroll
        for (int r = 0; r < 4; ++r)
            lds_O[(w * 16 + quad * 4 + r) * 64 + nt * 16 + l16] = oacc[nt][r];
    __syncthreads();

    // wave w merges rows w*4 .. w*4+3; lane = col.
#pragma unroll
    for (int rr = 0; rr < 4; ++rr) {
        const int row = w * 4 + rr;
        float M = -3.0e38f;
#pragma unroll
        for (int c = 0; c < 4; ++c) M = fmaxf(M, lds_m[c * 16 + row]);
        float L = 0.0f, O = 0.0f;
#pragma unroll
        for (int c = 0; c < 4; ++c) {
            const float e = __expf(lds_m[c * 16 + row] - M);
            L += e * lds_l[c * 16 + row];
            O += e * lds_O[(c * 16 + row) * 64 + lane];
        }
        out[(size_t)(b * 2048 + r0 + row) * 64 + lane] = O / L;
    }
}

extern "C" void kernel_launch(void* const* d_in, const int* in_sizes, int n_in,
                              void* d_out, int out_size, void* d_ws, size_t ws_size,
                              hipStream_t stream) {
    const float* x = (const float*)d_in[0];
    const float* Wq = (const float*)d_in[1];
    const float* Wk = (const float*)d_in[2];
    const float* Wv = (const float*)d_in[3];
    float* out = (float*)d_out;

    char* ws = (char*)d_ws;
    unsigned short* wtf = (unsigned short*)(ws);
    unsigned short* qf = (unsigned short*)(ws + 393216);
    unsigned short* kf = (unsigned short*)(ws + 1441792);
    unsigned short* vf = (unsigned short*)(ws + 2490368);

    hipLaunchKernelGGL(wt_kernel, dim3(48), dim3(256), 0, stream, Wq, Wk, Wv, wtf);
    hipLaunchKernelGGL(qkv_kernel, dim3(512), dim3(256), 0, stream, x, wtf, qf, kf, vf);
    hipLaunchKernelGGL(attn_kernel, dim3(512), dim3(256), 0, stream, qf, kf, vf, out);
}